// Round 13
// baseline (248.899 us; speedup 1.0000x reference)
//
#include <hip/hip_runtime.h>
#include <hip/hip_bf16.h>

typedef unsigned short u16;
typedef __bf16 bf16x8 __attribute__((ext_vector_type(8)));
typedef float f32x4 __attribute__((ext_vector_type(4)));

__device__ __forceinline__ float bf2f(u16 u) {
  union { unsigned int i; float f; } v; v.i = ((unsigned int)u) << 16; return v.f;
}
__device__ __forceinline__ u16 f2bf(float f) {
  union { float f; unsigned int i; } v; v.f = f;
  unsigned int r = v.i + 0x7fffu + ((v.i >> 16) & 1u);
  return (u16)(r >> 16);
}
__device__ __forceinline__ unsigned cvtpk(float lo, float hi) {
  unsigned r;
  asm("v_cvt_pk_bf16_f32 %0, %1, %2" : "=v"(r) : "v"(lo), "v"(hi));
  return r;
}

__device__ __forceinline__ void async_load16(void* lds, const void* g) {
  __builtin_amdgcn_global_load_lds((const __attribute__((address_space(1))) void*)g,
                                   (__attribute__((address_space(3))) void*)lds, 16, 0, 0);
}

#define BARRIER() do { asm volatile("" ::: "memory"); __builtin_amdgcn_s_barrier(); \
                       asm volatile("" ::: "memory"); } while (0)
#define LGKM0_PIN() do { asm volatile("s_waitcnt lgkmcnt(0)" ::: "memory"); \
                         __builtin_amdgcn_sched_barrier(0); } while (0)

// ---------------- fused fp32 -> bf16 convert (x, Wq|Wk -> Wqk, Wv, Wo) ----------------
__global__ void convert_all(const float* __restrict__ x, const float* __restrict__ Wq,
                            const float* __restrict__ Wk, const float* __restrict__ Wv,
                            const float* __restrict__ Wo, u16* __restrict__ xb,
                            u16* __restrict__ Wqkb, u16* __restrict__ Wvb,
                            u16* __restrict__ Wob) {
  int bid = blockIdx.x;
  const float* src;
  u16* dst;
  int off;
  if (bid < 8192)       { src = x;  dst = xb;              off = bid; }
  else if (bid < 12288) { src = Wq; dst = Wqkb;            off = bid - 8192; }
  else if (bid < 16384) { src = Wk; dst = Wqkb + 4194304;  off = bid - 12288; }
  else if (bid < 20480) { src = Wv; dst = Wvb;             off = bid - 16384; }
  else                  { src = Wo; dst = Wob;             off = bid - 20480; }
  int i = off * 1024 + threadIdx.x * 4;
  float4 v = *(const float4*)(src + i);
  ushort4 o;
  o.x = f2bf(v.x); o.y = f2bf(v.y); o.z = f2bf(v.z); o.w = f2bf(v.w);
  *(ushort4*)(dst + i) = o;
}

// ======== QK: 256x256 8-phase GEMM, BK=64, rope-fused epilogue (stable r12) ========
__device__ __forceinline__ void gemm_qk_8phase(const u16* __restrict__ A,
                                               const u16* __restrict__ Bm,
                                               u16* __restrict__ C, int K,
                                               int tm, int tn, u16* lds,
                                               const float* __restrict__ cosb,
                                               const float* __restrict__ sinb,
                                               float qscale) {
  const int NK = K >> 6;  // 32
  const int t = threadIdx.x;
  const int w = t >> 6, l = t & 63;
  const int wm = w >> 2, wn = w & 3;
  const int lr = l & 15, lh = l >> 4;
  const size_t row0 = (size_t)tm * 256, col0 = (size_t)tn * 256;
  const u16* Ag = A + row0 * K;
  const u16* Bg = Bm + col0 * K;

  auto stage_half = [&](int T, int h) {  // h: 0=A0 1=A1 2=B0 3=B1 (2 loads/thread)
    u16* dst = lds + (T & 1) * 32768 + h * 8192;
    const u16* src = (h < 2) ? (Ag + (size_t)(h * 128) * K)
                             : (Bg + (size_t)((h - 2) * 128) * K);
    const int kb = T * 64;
#pragma unroll
    for (int it = 0; it < 2; ++it) {
      int o = it * 8192 + t * 16;
      int r = o >> 7;
      int cbs = (o & 127) ^ ((r & 7) << 4);
      async_load16(dst + (o >> 1), src + (size_t)r * K + kb + (cbs >> 1));
    }
  };

  bf16x8 afq[4][2], bLo[2][2], bHi[2][2];
  f32x4 acc[8][4];
#pragma unroll
  for (int i = 0; i < 8; ++i)
#pragma unroll
    for (int j = 0; j < 4; ++j) acc[i][j] = (f32x4){0.f, 0.f, 0.f, 0.f};

  auto read_a = [&](int T, int mh) {
    const u16* sub = lds + (T & 1) * 32768 + wm * 8192;
#pragma unroll
    for (int mi = 0; mi < 4; ++mi) {
      int r = (mh * 4 + mi) * 16 + lr;
      int bb = r * 128, xr = (r & 7) << 4;
#pragma unroll
      for (int ks = 0; ks < 2; ++ks)
        afq[mi][ks] = *reinterpret_cast<const bf16x8*>(
            sub + ((bb + ((ks * 64 + lh * 16) ^ xr)) >> 1));
    }
  };
  auto read_b = [&](bf16x8 (*dst)[2], int T, int nh) {
    const u16* sub = lds + (T & 1) * 32768 + (2 + (wn >> 1)) * 8192;
#pragma unroll
    for (int nj2 = 0; nj2 < 2; ++nj2) {
      int nj = nh * 2 + nj2;
      int c = (wn & 1) * 32 + (nj & 1) * 16 + (nj >> 1) * 64 + lr;
      int bb = c * 128, xr = (c & 7) << 4;
#pragma unroll
      for (int ks = 0; ks < 2; ++ks)
        dst[nj2][ks] = *reinterpret_cast<const bf16x8*>(
            sub + ((bb + ((ks * 64 + lh * 16) ^ xr)) >> 1));
    }
  };
  auto mfma_q = [&](bf16x8 (*bq)[2], int mh, int nh) {
    __builtin_amdgcn_s_setprio(1);
#pragma unroll
    for (int ks = 0; ks < 2; ++ks)
#pragma unroll
      for (int mi = 0; mi < 4; ++mi)
#pragma unroll
        for (int nj2 = 0; nj2 < 2; ++nj2)
          acc[mh * 4 + mi][nh * 2 + nj2] = __builtin_amdgcn_mfma_f32_16x16x32_bf16(
              afq[mi][ks], bq[nj2][ks], acc[mh * 4 + mi][nh * 2 + nj2], 0, 0, 0);
    __builtin_amdgcn_s_setprio(0);
  };

  stage_half(0, 2); stage_half(0, 0); stage_half(0, 1); stage_half(0, 3);
  stage_half(1, 2); stage_half(1, 0);
  asm volatile("s_waitcnt vmcnt(4)" ::: "memory");
  BARRIER();

  for (int T = 0; T < NK; ++T) {
    read_a(T, 0);
    read_b(bLo, T, 0);
    if (T + 1 < NK) stage_half(T + 1, 1);
    asm volatile("s_waitcnt lgkmcnt(8)" ::: "memory");
    BARRIER();
    LGKM0_PIN();
    mfma_q(bLo, 0, 0);
    BARRIER();
    read_b(bHi, T, 1);
    if (T + 1 < NK) stage_half(T + 1, 3);
    BARRIER();
    LGKM0_PIN();
    mfma_q(bHi, 0, 1);
    BARRIER();
    read_a(T, 1);
    if (T + 2 < NK) stage_half(T + 2, 2);
    BARRIER();
    LGKM0_PIN();
    mfma_q(bLo, 1, 0);
    BARRIER();
    if (T + 2 < NK) stage_half(T + 2, 0);
    if (T + 1 <= NK - 2)      asm volatile("s_waitcnt vmcnt(4)" ::: "memory");
    else if (T + 1 == NK - 1) asm volatile("s_waitcnt vmcnt(0)" ::: "memory");
    BARRIER();
    mfma_q(bHi, 1, 1);
    BARRIER();
  }

  float scale = (2 * tn + (wn >> 1)) < 16 ? qscale : 1.0f;
  size_t colbase = col0 + (wn >> 1) * 128;
#pragma unroll
  for (int mi = 0; mi < 8; ++mi)
#pragma unroll
    for (int r = 0; r < 4; ++r) {
      size_t row = row0 + wm * 128 + mi * 16 + lh * 4 + r;
      int si = (int)(row & 2047);
      const float* cr = cosb + si * 128;
      const float* sr = sinb + si * 128;
#pragma unroll
      for (int ni = 0; ni < 2; ++ni) {
        int dlo = (wn & 1) * 32 + ni * 16 + lr;
        float v0 = acc[mi][ni][r];
        float v1 = acc[mi][ni + 2][r];
        float o0 = (v0 * cr[dlo] - v1 * sr[dlo]) * scale;
        float o1 = (v1 * cr[64 + dlo] + v0 * sr[64 + dlo]) * scale;
        C[row * 4096 + colbase + dlo]      = f2bf(o0);
        C[row * 4096 + colbase + 64 + dlo] = f2bf(o1);
      }
    }
}

// ======== pipelined body (ring-4 BK=32) — V^T and gemm_o (stable) ========
template <int BMHALF, int OUT_F32>
__device__ __forceinline__ void gemm_pipe_body(const u16* __restrict__ A,
                                               const u16* __restrict__ Bm,
                                               void* __restrict__ C, int M, int N, int K,
                                               int tm, int tn, u16* lds) {
  constexpr int MIc = BMHALF / 16;
  constexpr int SUBU16 = (BMHALF == 128) ? 16384 : 12288;
  constexpr int BOFF = (BMHALF == 128) ? 8192 : 4096;
  const int t = threadIdx.x;
  const int w = t >> 6, l = t & 63;
  const int wm = w >> 2, wn = w & 3;
  const int lr = l & 15, lh = l >> 4;
  const size_t row0 = (size_t)tm * (2 * BMHALF), col0 = (size_t)tn * 256;
  const u16* Ag = A + row0 * K;
  const u16* Bg = Bm + col0 * K;

  const int ra = t >> 2;
  const int kcs = ((t & 3) << 3) ^ ((ra & 6) << 2);
  auto stage = [&](int s) {
    u16* dst = lds + (s & 3) * SUBU16;
    const size_t koff = (size_t)s * 32 + kcs;
    if constexpr (BMHALF == 128) {
      async_load16(dst + t * 8,         Ag + (size_t)ra * K + koff);
      async_load16(dst + 4096 + t * 8,  Ag + (size_t)(ra + 128) * K + koff);
      async_load16(dst + 8192 + t * 8,  Bg + (size_t)ra * K + koff);
      async_load16(dst + 12288 + t * 8, Bg + (size_t)(ra + 128) * K + koff);
    } else {
      async_load16(dst + t * 8,         Ag + (size_t)ra * K + koff);
      async_load16(dst + 4096 + t * 8,  Bg + (size_t)ra * K + koff);
      async_load16(dst + 8192 + t * 8,  Bg + (size_t)(ra + 128) * K + koff);
    }
  };
  const int swl = (lh * 8) ^ ((lr & 6) << 2);
  auto read_af = [&](bf16x8* dst, int s) {
    const u16* sub = lds + (s & 3) * SUBU16;
#pragma unroll
    for (int mi = 0; mi < MIc; ++mi)
      dst[mi] = *reinterpret_cast<const bf16x8*>(sub + (wm * BMHALF + mi * 16 + lr) * 32 + swl);
  };
  auto read_bfv = [&](bf16x8* dst, int s) {
    const u16* sub = lds + (s & 3) * SUBU16 + BOFF;
#pragma unroll
    for (int ni = 0; ni < 4; ++ni)
      dst[ni] = *reinterpret_cast<const bf16x8*>(sub + (wn * 64 + ni * 16 + lr) * 32 + swl);
  };

  f32x4 acc[MIc][4];
#pragma unroll
  for (int i = 0; i < MIc; ++i)
#pragma unroll
    for (int j = 0; j < 4; ++j) acc[i][j] = (f32x4){0.f, 0.f, 0.f, 0.f};

  const int NK = K >> 5;
  bf16x8 afA[MIc], afB[MIc], bfvA[4], bfvB[4];

  stage(0); stage(1); stage(2);
  if constexpr (BMHALF == 128) asm volatile("s_waitcnt vmcnt(8)" ::: "memory");
  else                         asm volatile("s_waitcnt vmcnt(6)" ::: "memory");
  BARRIER();
  read_af(afA, 0);
  read_bfv(bfvA, 0);

  auto pipestep = [&](int s, bf16x8* curA, bf16x8* curB, bf16x8* nxtA, bf16x8* nxtB) {
    if (s + 2 < NK) {
      if constexpr (BMHALF == 128) asm volatile("s_waitcnt vmcnt(4)" ::: "memory");
      else                         asm volatile("s_waitcnt vmcnt(3)" ::: "memory");
    } else {
      asm volatile("s_waitcnt vmcnt(0)" ::: "memory");
    }
    BARRIER();
    if (s + 3 < NK) stage(s + 3);
    if (s + 1 < NK) {
      read_af(nxtA, s + 1);
      read_bfv(nxtB, s + 1);
    }
    __builtin_amdgcn_s_setprio(1);
#pragma unroll
    for (int mi = 0; mi < MIc; ++mi)
#pragma unroll
      for (int ni = 0; ni < 4; ++ni)
        acc[mi][ni] = __builtin_amdgcn_mfma_f32_16x16x32_bf16(curA[mi], curB[ni], acc[mi][ni], 0, 0, 0);
    __builtin_amdgcn_s_setprio(0);
  };

  for (int s = 0; s < NK; s += 2) {
    pipestep(s,     afA, bfvA, afB, bfvB);
    pipestep(s + 1, afB, bfvB, afA, bfvA);
  }

#pragma unroll
  for (int mi = 0; mi < MIc; ++mi)
#pragma unroll
    for (int ni = 0; ni < 4; ++ni)
#pragma unroll
      for (int r = 0; r < 4; ++r) {
        size_t row = row0 + wm * BMHALF + mi * 16 + lh * 4 + r;
        size_t col = col0 + wn * 64 + ni * 16 + lr;
        float v = acc[mi][ni][r];
        if (OUT_F32)
          ((float*)C)[row * N + col] = v;
        else
          ((u16*)C)[row * N + col] = f2bf(v);
      }
}

// QK (256 blocks, 8-phase 256x256, rope fused) + V^T (256 blocks, 128x256 pipe)
__global__ __launch_bounds__(512, 2)
void gemm_qkv256(const u16* __restrict__ xb, const u16* __restrict__ Wqkb,
                 const u16* __restrict__ Wvb, u16* __restrict__ QKb, u16* __restrict__ VTb,
                 const float* __restrict__ cosb, const float* __restrict__ sinb,
                 float qscale) {
  __shared__ __align__(16) u16 lds[65536];  // 128 KB
  int bid = blockIdx.x;
  if (bid < 256) {
    int swz = (bid & 7) * 32 + (bid >> 3);
    gemm_qk_8phase(xb, Wqkb, QKb, 2048, swz >> 4, swz & 15, lds, cosb, sinb, qscale);
  } else {
    int b2 = bid - 256;
    int swz = (b2 & 7) * 32 + (b2 >> 3);
    gemm_pipe_body<64, 0>(Wvb, xb, VTb, 2048, 4096, 2048, swz >> 4, swz & 15, lds);
  }
}

// out = O @ Wo^T (fp32 out): 256 blocks of 128x256 = 1 exact round
__global__ __launch_bounds__(512, 2)
void gemm_o(const u16* __restrict__ Ob, const u16* __restrict__ Wob, float* __restrict__ out) {
  __shared__ __align__(16) u16 lds[4 * 12288];
  int bid = blockIdx.x;
  int swz = (bid & 7) * 32 + (bid >> 3);
  gemm_pipe_body<64, 1>(Ob, Wob, (void*)out, 4096, 2048, 2048, swz >> 3, swz & 7, lds);
}

// ---------------- Flash attention: 512-thread blocks, 256 q-rows, 1 block/CU ----------
// QK: [B*S][4096] bf16 (cols 0-2047 = roped*scaled Q, 2048-4095 = roped K).
// VT: [2048][4096] bf16. O: [B*S][2048] bf16.
// grid 256 = 32 bh * 8 qtiles(256 rows) = exact 1 round; block 512 = 8 waves x 32 q.
// LDS 96KB: K dbuf 32K + V dbuf 32K + sP 8x4K. Per KV tile: stage(next) at top
// (4 loads/thread), QK^T -> in-lane softmax -> P via sP -> PV, ONE __syncthreads.
// vs 256-thr version: 2x compute per tile hides the same prefetch latency, KV
// staging traffic halved (staged once per 256 q-rows), barrier rate halved.
__global__ __launch_bounds__(512, 2)
void attn_kernel(const u16* __restrict__ QKb, const u16* __restrict__ VT,
                 u16* __restrict__ Ob) {
  __shared__ __align__(16) u16 sK[2][64 * 128];   // 32 KB
  __shared__ __align__(16) u16 sV[2][128 * 64];   // 32 KB
  __shared__ __align__(16) u16 sP[8][32 * 64];    // 32 KB

  int id = blockIdx.x;
  int swz = (id & 7) * 32 + (id >> 3);    // XCD-chunked: 4 heads/XCD
  int bh = swz >> 3;
  int qt = swz & 7;
  int b = bh >> 4, h = bh & 15;
  int t = threadIdx.x, w = t >> 6, l = t & 63;
  int lr = l & 15, lh = l >> 4;
  int lr7 = lr & 7;
  int q0 = qt * 256;

  const u16* Kbase = QKb + (size_t)(b * 2048) * 4096 + 2048 + h * 128;
  const u16* Vbase = VT + (size_t)(h * 128) * 4096 + b * 2048;
  u16* sPw = sP[w];

  bf16x8 aq[2][4];
#pragma unroll
  for (int qf = 0; qf < 2; ++qf) {
    size_t qrow = (size_t)(b * 2048 + q0 + w * 32 + qf * 16 + lr) * 4096 + h * 128;
#pragma unroll
    for (int c = 0; c < 4; ++c)
      aq[qf][c] = *reinterpret_cast<const bf16x8*>(QKb + qrow + c * 32 + lh * 8);
  }

  f32x4 zero = {0.f, 0.f, 0.f, 0.f};
  f32x4 acc_o[2][8];  // O^T[d][q=lr]
#pragma unroll
  for (int qf = 0; qf < 2; ++qf)
#pragma unroll
    for (int d = 0; d < 8; ++d) acc_o[qf][d] = zero;
  float m_row[2] = {-1e30f, -1e30f};
  float l_row[2] = {0.f, 0.f};

  // 512 threads: 2 its x 16B cover each 16KB tile (4 loads/thread total)
  auto stage = [&](int buf, int kt2) {
    const u16* Kt = Kbase + (size_t)(kt2 * 64) * 4096;
    const u16* Vt = Vbase + kt2 * 64;
#pragma unroll
    for (int it = 0; it < 2; ++it) {
      int o = it * 8192 + t * 16;            // byte offset in 16KB tile
      int rowK = o >> 8;
      int cbK = (o & 255) ^ ((rowK & 7) << 4);
      async_load16((u16*)sK[buf] + (o >> 1), Kt + (size_t)rowK * 4096 + (cbK >> 1));
      int rowV = o >> 7;
      int cbV = (o & 127) ^ ((rowV & 7) << 4);
      async_load16((u16*)sV[buf] + (o >> 1), Vt + (size_t)rowV * 4096 + (cbV >> 1));
    }
  };

  stage(0, 0);
  __syncthreads();
  int cur = 0;

  for (int kt = 0; kt < 32; ++kt) {
    if (kt < 31) stage(cur ^ 1, kt + 1);

    const u16* sKc = sK[cur];
    const u16* sVc = sV[cur];

    f32x4 sacc[2][4];
#pragma unroll
    for (int qf = 0; qf < 2; ++qf)
#pragma unroll
      for (int g = 0; g < 4; ++g) sacc[qf][g] = zero;
    __builtin_amdgcn_s_setprio(1);
#pragma unroll
    for (int g = 0; g < 4; ++g) {
      int row = g * 16 + lr;
      int xr = lr7 << 4;
#pragma unroll
      for (int c = 0; c < 4; ++c) {
        int cb = (c * 64 + lh * 16) ^ xr;
        bf16x8 bk = *reinterpret_cast<const bf16x8*>(sKc + row * 128 + (cb >> 1));
        sacc[0][g] = __builtin_amdgcn_mfma_f32_16x16x32_bf16(bk, aq[0][c], sacc[0][g], 0, 0, 0);
        sacc[1][g] = __builtin_amdgcn_mfma_f32_16x16x32_bf16(bk, aq[1][c], sacc[1][g], 0, 0, 0);
      }
    }
    __builtin_amdgcn_s_setprio(0);

#pragma unroll
    for (int qf = 0; qf < 2; ++qf) {
      f32x4 m4;
#pragma unroll
      for (int e = 0; e < 4; ++e)
        m4[e] = fmaxf(fmaxf(sacc[qf][0][e], sacc[qf][1][e]),
                      fmaxf(sacc[qf][2][e], sacc[qf][3][e]));
      float mx = fmaxf(fmaxf(m4[0], m4[1]), fmaxf(m4[2], m4[3]));
      mx = fmaxf(mx, __shfl_xor(mx, 16));
      mx = fmaxf(mx, __shfl_xor(mx, 32));
      float mo = m_row[qf];
      if (!__all(mx <= mo + 8.f)) {     // T13 defer-max
        float mn = fmaxf(mo, mx);
        float al = __builtin_amdgcn_exp2f(mo - mn);
        m_row[qf] = mn;
        l_row[qf] *= al;
#pragma unroll
        for (int d = 0; d < 8; ++d) acc_o[qf][d] *= al;
      }
      float mn = m_row[qf];
#pragma unroll
      for (int g = 0; g < 4; ++g)
#pragma unroll
        for (int e = 0; e < 4; ++e)
          sacc[qf][g][e] = __builtin_amdgcn_exp2f(sacc[qf][g][e] - mn);
      f32x4 s4;
#pragma unroll
      for (int e = 0; e < 4; ++e)
        s4[e] = (sacc[qf][0][e] + sacc[qf][1][e]) + (sacc[qf][2][e] + sacc[qf][3][e]);
      float rs = (s4[0] + s4[1]) + (s4[2] + s4[3]);
      rs += __shfl_xor(rs, 16);
      rs += __shfl_xor(rs, 32);
      l_row[qf] += rs;

      int rowb = (qf * 16 + lr) * 128;
      int xw = lr7 << 4;
#pragma unroll
      for (int g = 0; g < 4; ++g) {
        uint2 pw;
        pw.x = cvtpk(sacc[qf][g][0], sacc[qf][g][1]);
        pw.y = cvtpk(sacc[qf][g][2], sacc[qf][g][3]);
        int cb = (g * 32 + lh * 8) ^ xw;
        *reinterpret_cast<uint2*>(reinterpret_cast<char*>(sPw) + rowb + cb) = pw;
      }
    }

    bf16x8 bp[2][2];
#pragma unroll
    for (int qf = 0; qf < 2; ++qf) {
      int rowb = (qf * 16 + lr) * 128;
      int xr = lr7 << 4;
#pragma unroll
      for (int c2 = 0; c2 < 2; ++c2) {
        int cb = (c2 * 64 + lh * 16) ^ xr;
        bp[qf][c2] = *reinterpret_cast<const bf16x8*>(
            reinterpret_cast<const char*>(sPw) + rowb + cb);
      }
    }
    __builtin_amdgcn_s_setprio(1);
#pragma unroll
    for (int c2 = 0; c2 < 2; ++c2) {
#pragma unroll
      for (int d = 0; d < 8; ++d) {
        int row = d * 16 + lr;
        int cb = (c2 * 64 + lh * 16) ^ (lr7 << 4);
        bf16x8 bv = *reinterpret_cast<const bf16x8*>(sVc + row * 64 + (cb >> 1));
        acc_o[0][d] = __builtin_amdgcn_mfma_f32_16x16x32_bf16(bv, bp[0][c2], acc_o[0][d], 0, 0, 0);
        acc_o[1][d] = __builtin_amdgcn_mfma_f32_16x16x32_bf16(bv, bp[1][c2], acc_o[1][d], 0, 0, 0);
      }
    }
    __builtin_amdgcn_s_setprio(0);

    __syncthreads();
    cur ^= 1;
  }

#pragma unroll
  for (int qf = 0; qf < 2; ++qf) {
    float inv = 1.f / l_row[qf];
    size_t qrow = (size_t)(b * 2048 + q0 + w * 32 + qf * 16 + lr) * 2048 + h * 128;
#pragma unroll
    for (int d = 0; d < 8; ++d) {
      ushort4 o;
      o.x = f2bf(acc_o[qf][d][0] * inv);
      o.y = f2bf(acc_o[qf][d][1] * inv);
      o.z = f2bf(acc_o[qf][d][2] * inv);
      o.w = f2bf(acc_o[qf][d][3] * inv);
      *reinterpret_cast<ushort4*>(Ob + qrow + d * 16 + lh * 4) = o;
    }
  }
}

extern "C" void kernel_launch(void* const* d_in, const int* in_sizes, int n_in,
                              void* d_out, int out_size, void* d_ws, size_t ws_size,
                              hipStream_t stream) {
  const float* x  = (const float*)d_in[0];
  const float* rc = (const float*)d_in[1];
  const float* rs = (const float*)d_in[2];
  const float* Wq = (const float*)d_in[3];
  const float* Wk = (const float*)d_in[4];
  const float* Wv = (const float*)d_in[5];
  const float* Wo = (const float*)d_in[6];
  float* out = (float*)d_out;
  char* ws = (char*)d_ws;
  const size_t MB = 1024 * 1024;
  u16* xb   = (u16*)(ws);            // 16 MB
  u16* Wqkb = (u16*)(ws + 16 * MB);  // 16 MB  [4096][2048] = [Wq;Wk]
  u16* Wvb  = (u16*)(ws + 32 * MB);  // 8 MB
  u16* Wob  = (u16*)(ws + 40 * MB);  // 8 MB
  u16* QKb  = (u16*)(ws + 48 * MB);  // 32 MB  [4096][4096]
  u16* VTb  = (u16*)(ws + 80 * MB);  // 16 MB  [2048][4096]
  u16* Ob   = (u16*)(ws + 16 * MB);  // 16 MB  (alias Wqkb, dead after QK GEMM)

  convert_all<<<24576, 256, 0, stream>>>(x, Wq, Wk, Wv, Wo, xb, Wqkb, Wvb, Wob);

  const float qscale = 0.08838834764831845f * 1.4426950408889634f;  // 1/sqrt(128)*log2(e)
  gemm_qkv256<<<512, 512, 0, stream>>>(xb, Wqkb, Wvb, QKb, VTb, rc, rs, qscale);

  attn_kernel<<<256, 512, 0, stream>>>(QKb, VTb, Ob);

  gemm_o<<<256, 512, 0, stream>>>(Ob, Wob, out);
}

// Round 14
// 241.294 us; speedup vs baseline: 1.0315x; 1.0315x over previous
//
#include <hip/hip_runtime.h>
#include <hip/hip_bf16.h>

typedef unsigned short u16;
typedef __bf16 bf16x8 __attribute__((ext_vector_type(8)));
typedef float f32x4 __attribute__((ext_vector_type(4)));

__device__ __forceinline__ float bf2f(u16 u) {
  union { unsigned int i; float f; } v; v.i = ((unsigned int)u) << 16; return v.f;
}
__device__ __forceinline__ u16 f2bf(float f) {
  union { float f; unsigned int i; } v; v.f = f;
  unsigned int r = v.i + 0x7fffu + ((v.i >> 16) & 1u);
  return (u16)(r >> 16);
}
__device__ __forceinline__ unsigned cvtpk(float lo, float hi) {
  unsigned r;
  asm("v_cvt_pk_bf16_f32 %0, %1, %2" : "=v"(r) : "v"(lo), "v"(hi));
  return r;
}

__device__ __forceinline__ void async_load16(void* lds, const void* g) {
  __builtin_amdgcn_global_load_lds((const __attribute__((address_space(1))) void*)g,
                                   (__attribute__((address_space(3))) void*)lds, 16, 0, 0);
}

#define BARRIER() do { asm volatile("" ::: "memory"); __builtin_amdgcn_s_barrier(); \
                       asm volatile("" ::: "memory"); } while (0)
#define LGKM0_PIN() do { asm volatile("s_waitcnt lgkmcnt(0)" ::: "memory"); \
                         __builtin_amdgcn_sched_barrier(0); } while (0)

// ---------------- fused fp32 -> bf16 convert (x, Wq|Wk -> Wqk, Wv, Wo) ----------------
__global__ void convert_all(const float* __restrict__ x, const float* __restrict__ Wq,
                            const float* __restrict__ Wk, const float* __restrict__ Wv,
                            const float* __restrict__ Wo, u16* __restrict__ xb,
                            u16* __restrict__ Wqkb, u16* __restrict__ Wvb,
                            u16* __restrict__ Wob) {
  int bid = blockIdx.x;
  const float* src;
  u16* dst;
  int off;
  if (bid < 8192)       { src = x;  dst = xb;              off = bid; }
  else if (bid < 12288) { src = Wq; dst = Wqkb;            off = bid - 8192; }
  else if (bid < 16384) { src = Wk; dst = Wqkb + 4194304;  off = bid - 12288; }
  else if (bid < 20480) { src = Wv; dst = Wvb;             off = bid - 16384; }
  else                  { src = Wo; dst = Wob;             off = bid - 20480; }
  int i = off * 1024 + threadIdx.x * 4;
  float4 v = *(const float4*)(src + i);
  ushort4 o;
  o.x = f2bf(v.x); o.y = f2bf(v.y); o.z = f2bf(v.z); o.w = f2bf(v.w);
  *(ushort4*)(dst + i) = o;
}

// ======== QK: 256x256 8-phase GEMM, BK=64, rope-fused epilogue (stable r12) ========
__device__ __forceinline__ void gemm_qk_8phase(const u16* __restrict__ A,
                                               const u16* __restrict__ Bm,
                                               u16* __restrict__ C, int K,
                                               int tm, int tn, u16* lds,
                                               const float* __restrict__ cosb,
                                               const float* __restrict__ sinb,
                                               float qscale) {
  const int NK = K >> 6;  // 32
  const int t = threadIdx.x;
  const int w = t >> 6, l = t & 63;
  const int wm = w >> 2, wn = w & 3;
  const int lr = l & 15, lh = l >> 4;
  const size_t row0 = (size_t)tm * 256, col0 = (size_t)tn * 256;
  const u16* Ag = A + row0 * K;
  const u16* Bg = Bm + col0 * K;

  auto stage_half = [&](int T, int h) {  // h: 0=A0 1=A1 2=B0 3=B1 (2 loads/thread)
    u16* dst = lds + (T & 1) * 32768 + h * 8192;
    const u16* src = (h < 2) ? (Ag + (size_t)(h * 128) * K)
                             : (Bg + (size_t)((h - 2) * 128) * K);
    const int kb = T * 64;
#pragma unroll
    for (int it = 0; it < 2; ++it) {
      int o = it * 8192 + t * 16;
      int r = o >> 7;
      int cbs = (o & 127) ^ ((r & 7) << 4);
      async_load16(dst + (o >> 1), src + (size_t)r * K + kb + (cbs >> 1));
    }
  };

  bf16x8 afq[4][2], bLo[2][2], bHi[2][2];
  f32x4 acc[8][4];
#pragma unroll
  for (int i = 0; i < 8; ++i)
#pragma unroll
    for (int j = 0; j < 4; ++j) acc[i][j] = (f32x4){0.f, 0.f, 0.f, 0.f};

  auto read_a = [&](int T, int mh) {
    const u16* sub = lds + (T & 1) * 32768 + wm * 8192;
#pragma unroll
    for (int mi = 0; mi < 4; ++mi) {
      int r = (mh * 4 + mi) * 16 + lr;
      int bb = r * 128, xr = (r & 7) << 4;
#pragma unroll
      for (int ks = 0; ks < 2; ++ks)
        afq[mi][ks] = *reinterpret_cast<const bf16x8*>(
            sub + ((bb + ((ks * 64 + lh * 16) ^ xr)) >> 1));
    }
  };
  auto read_b = [&](bf16x8 (*dst)[2], int T, int nh) {
    const u16* sub = lds + (T & 1) * 32768 + (2 + (wn >> 1)) * 8192;
#pragma unroll
    for (int nj2 = 0; nj2 < 2; ++nj2) {
      int nj = nh * 2 + nj2;
      int c = (wn & 1) * 32 + (nj & 1) * 16 + (nj >> 1) * 64 + lr;
      int bb = c * 128, xr = (c & 7) << 4;
#pragma unroll
      for (int ks = 0; ks < 2; ++ks)
        dst[nj2][ks] = *reinterpret_cast<const bf16x8*>(
            sub + ((bb + ((ks * 64 + lh * 16) ^ xr)) >> 1));
    }
  };
  auto mfma_q = [&](bf16x8 (*bq)[2], int mh, int nh) {
    __builtin_amdgcn_s_setprio(1);
#pragma unroll
    for (int ks = 0; ks < 2; ++ks)
#pragma unroll
      for (int mi = 0; mi < 4; ++mi)
#pragma unroll
        for (int nj2 = 0; nj2 < 2; ++nj2)
          acc[mh * 4 + mi][nh * 2 + nj2] = __builtin_amdgcn_mfma_f32_16x16x32_bf16(
              afq[mi][ks], bq[nj2][ks], acc[mh * 4 + mi][nh * 2 + nj2], 0, 0, 0);
    __builtin_amdgcn_s_setprio(0);
  };

  stage_half(0, 2); stage_half(0, 0); stage_half(0, 1); stage_half(0, 3);
  stage_half(1, 2); stage_half(1, 0);
  asm volatile("s_waitcnt vmcnt(4)" ::: "memory");
  BARRIER();

  for (int T = 0; T < NK; ++T) {
    read_a(T, 0);
    read_b(bLo, T, 0);
    if (T + 1 < NK) stage_half(T + 1, 1);
    asm volatile("s_waitcnt lgkmcnt(8)" ::: "memory");
    BARRIER();
    LGKM0_PIN();
    mfma_q(bLo, 0, 0);
    BARRIER();
    read_b(bHi, T, 1);
    if (T + 1 < NK) stage_half(T + 1, 3);
    BARRIER();
    LGKM0_PIN();
    mfma_q(bHi, 0, 1);
    BARRIER();
    read_a(T, 1);
    if (T + 2 < NK) stage_half(T + 2, 2);
    BARRIER();
    LGKM0_PIN();
    mfma_q(bLo, 1, 0);
    BARRIER();
    if (T + 2 < NK) stage_half(T + 2, 0);
    if (T + 1 <= NK - 2)      asm volatile("s_waitcnt vmcnt(4)" ::: "memory");
    else if (T + 1 == NK - 1) asm volatile("s_waitcnt vmcnt(0)" ::: "memory");
    BARRIER();
    mfma_q(bHi, 1, 1);
    BARRIER();
  }

  float scale = (2 * tn + (wn >> 1)) < 16 ? qscale : 1.0f;
  size_t colbase = col0 + (wn >> 1) * 128;
#pragma unroll
  for (int mi = 0; mi < 8; ++mi)
#pragma unroll
    for (int r = 0; r < 4; ++r) {
      size_t row = row0 + wm * 128 + mi * 16 + lh * 4 + r;
      int si = (int)(row & 2047);
      const float* cr = cosb + si * 128;
      const float* sr = sinb + si * 128;
#pragma unroll
      for (int ni = 0; ni < 2; ++ni) {
        int dlo = (wn & 1) * 32 + ni * 16 + lr;
        float v0 = acc[mi][ni][r];
        float v1 = acc[mi][ni + 2][r];
        float o0 = (v0 * cr[dlo] - v1 * sr[dlo]) * scale;
        float o1 = (v1 * cr[64 + dlo] + v0 * sr[64 + dlo]) * scale;
        C[row * 4096 + colbase + dlo]      = f2bf(o0);
        C[row * 4096 + colbase + 64 + dlo] = f2bf(o1);
      }
    }
}

// ======== pipelined body (ring-4 BK=32) — V^T and gemm_o (stable) ========
template <int BMHALF, int OUT_F32>
__device__ __forceinline__ void gemm_pipe_body(const u16* __restrict__ A,
                                               const u16* __restrict__ Bm,
                                               void* __restrict__ C, int M, int N, int K,
                                               int tm, int tn, u16* lds) {
  constexpr int MIc = BMHALF / 16;
  constexpr int SUBU16 = (BMHALF == 128) ? 16384 : 12288;
  constexpr int BOFF = (BMHALF == 128) ? 8192 : 4096;
  const int t = threadIdx.x;
  const int w = t >> 6, l = t & 63;
  const int wm = w >> 2, wn = w & 3;
  const int lr = l & 15, lh = l >> 4;
  const size_t row0 = (size_t)tm * (2 * BMHALF), col0 = (size_t)tn * 256;
  const u16* Ag = A + row0 * K;
  const u16* Bg = Bm + col0 * K;

  const int ra = t >> 2;
  const int kcs = ((t & 3) << 3) ^ ((ra & 6) << 2);
  auto stage = [&](int s) {
    u16* dst = lds + (s & 3) * SUBU16;
    const size_t koff = (size_t)s * 32 + kcs;
    if constexpr (BMHALF == 128) {
      async_load16(dst + t * 8,         Ag + (size_t)ra * K + koff);
      async_load16(dst + 4096 + t * 8,  Ag + (size_t)(ra + 128) * K + koff);
      async_load16(dst + 8192 + t * 8,  Bg + (size_t)ra * K + koff);
      async_load16(dst + 12288 + t * 8, Bg + (size_t)(ra + 128) * K + koff);
    } else {
      async_load16(dst + t * 8,         Ag + (size_t)ra * K + koff);
      async_load16(dst + 4096 + t * 8,  Bg + (size_t)ra * K + koff);
      async_load16(dst + 8192 + t * 8,  Bg + (size_t)(ra + 128) * K + koff);
    }
  };
  const int swl = (lh * 8) ^ ((lr & 6) << 2);
  auto read_af = [&](bf16x8* dst, int s) {
    const u16* sub = lds + (s & 3) * SUBU16;
#pragma unroll
    for (int mi = 0; mi < MIc; ++mi)
      dst[mi] = *reinterpret_cast<const bf16x8*>(sub + (wm * BMHALF + mi * 16 + lr) * 32 + swl);
  };
  auto read_bfv = [&](bf16x8* dst, int s) {
    const u16* sub = lds + (s & 3) * SUBU16 + BOFF;
#pragma unroll
    for (int ni = 0; ni < 4; ++ni)
      dst[ni] = *reinterpret_cast<const bf16x8*>(sub + (wn * 64 + ni * 16 + lr) * 32 + swl);
  };

  f32x4 acc[MIc][4];
#pragma unroll
  for (int i = 0; i < MIc; ++i)
#pragma unroll
    for (int j = 0; j < 4; ++j) acc[i][j] = (f32x4){0.f, 0.f, 0.f, 0.f};

  const int NK = K >> 5;
  bf16x8 afA[MIc], afB[MIc], bfvA[4], bfvB[4];

  stage(0); stage(1); stage(2);
  if constexpr (BMHALF == 128) asm volatile("s_waitcnt vmcnt(8)" ::: "memory");
  else                         asm volatile("s_waitcnt vmcnt(6)" ::: "memory");
  BARRIER();
  read_af(afA, 0);
  read_bfv(bfvA, 0);

  auto pipestep = [&](int s, bf16x8* curA, bf16x8* curB, bf16x8* nxtA, bf16x8* nxtB) {
    if (s + 2 < NK) {
      if constexpr (BMHALF == 128) asm volatile("s_waitcnt vmcnt(4)" ::: "memory");
      else                         asm volatile("s_waitcnt vmcnt(3)" ::: "memory");
    } else {
      asm volatile("s_waitcnt vmcnt(0)" ::: "memory");
    }
    BARRIER();
    if (s + 3 < NK) stage(s + 3);
    if (s + 1 < NK) {
      read_af(nxtA, s + 1);
      read_bfv(nxtB, s + 1);
    }
    __builtin_amdgcn_s_setprio(1);
#pragma unroll
    for (int mi = 0; mi < MIc; ++mi)
#pragma unroll
      for (int ni = 0; ni < 4; ++ni)
        acc[mi][ni] = __builtin_amdgcn_mfma_f32_16x16x32_bf16(curA[mi], curB[ni], acc[mi][ni], 0, 0, 0);
    __builtin_amdgcn_s_setprio(0);
  };

  for (int s = 0; s < NK; s += 2) {
    pipestep(s,     afA, bfvA, afB, bfvB);
    pipestep(s + 1, afB, bfvB, afA, bfvA);
  }

#pragma unroll
  for (int mi = 0; mi < MIc; ++mi)
#pragma unroll
    for (int ni = 0; ni < 4; ++ni)
#pragma unroll
      for (int r = 0; r < 4; ++r) {
        size_t row = row0 + wm * BMHALF + mi * 16 + lh * 4 + r;
        size_t col = col0 + wn * 64 + ni * 16 + lr;
        float v = acc[mi][ni][r];
        if (OUT_F32)
          ((float*)C)[row * N + col] = v;
        else
          ((u16*)C)[row * N + col] = f2bf(v);
      }
}

// QK (256 blocks, 8-phase 256x256, rope fused) + V^T (256 blocks, 128x256 pipe)
__global__ __launch_bounds__(512, 2)
void gemm_qkv256(const u16* __restrict__ xb, const u16* __restrict__ Wqkb,
                 const u16* __restrict__ Wvb, u16* __restrict__ QKb, u16* __restrict__ VTb,
                 const float* __restrict__ cosb, const float* __restrict__ sinb,
                 float qscale) {
  __shared__ __align__(16) u16 lds[65536];  // 128 KB
  int bid = blockIdx.x;
  if (bid < 256) {
    int swz = (bid & 7) * 32 + (bid >> 3);
    gemm_qk_8phase(xb, Wqkb, QKb, 2048, swz >> 4, swz & 15, lds, cosb, sinb, qscale);
  } else {
    int b2 = bid - 256;
    int swz = (b2 & 7) * 32 + (b2 >> 3);
    gemm_pipe_body<64, 0>(Wvb, xb, VTb, 2048, 4096, 2048, swz >> 4, swz & 15, lds);
  }
}

// out = O @ Wo^T (fp32 out): 256 blocks of 128x256 = 1 exact round
__global__ __launch_bounds__(512, 2)
void gemm_o(const u16* __restrict__ Ob, const u16* __restrict__ Wob, float* __restrict__ out) {
  __shared__ __align__(16) u16 lds[4 * 12288];
  int bid = blockIdx.x;
  int swz = (bid & 7) * 32 + (bid >> 3);
  gemm_pipe_body<64, 1>(Ob, Wob, (void*)out, 4096, 2048, 2048, swz >> 3, swz & 7, lds);
}

// ---------------- Flash attention (r12 proven config: 256 thr, 2 blocks/CU) ----------
// QK: [B*S][4096] bf16 (cols 0-2047 = roped*scaled Q, 2048-4095 = roped K).
// VT: [2048][4096] bf16. O: [B*S][2048] bf16.
// grid 512 = 32 bh * 16 qtiles(128); block 256 = 4 waves * 32 q-rows (2 qf of 16).
// Swapped QK^T / PV, in-lane softmax, K+V double-buffered, __syncthreads per tile.
// 2 blocks/CU: co-resident block's MFMA covers this block's barrier drain (m114).
__global__ __launch_bounds__(256, 2)
void attn_kernel(const u16* __restrict__ QKb, const u16* __restrict__ VT,
                 u16* __restrict__ Ob) {
  __shared__ __align__(16) u16 sK[2][64 * 128];   // 32 KB
  __shared__ __align__(16) u16 sV[2][128 * 64];   // 32 KB
  __shared__ __align__(16) u16 sP[4][32 * 64];    // 16 KB

  int id = blockIdx.x;
  int swz = (id & 7) * 64 + (id >> 3);    // XCD-chunked: 4 heads/XCD -> KV L2-resident
  int bh = swz >> 4;
  int qb = swz & 15;
  int b = bh >> 4, h = bh & 15;
  int t = threadIdx.x, w = t >> 6, l = t & 63;
  int lr = l & 15, lh = l >> 4;
  int lr7 = lr & 7;
  int q0 = qb * 128;

  const u16* Kbase = QKb + (size_t)(b * 2048) * 4096 + 2048 + h * 128;
  const u16* Vbase = VT + (size_t)(h * 128) * 4096 + b * 2048;
  u16* sPw = sP[w];

  bf16x8 aq[2][4];
#pragma unroll
  for (int qf = 0; qf < 2; ++qf) {
    size_t qrow = (size_t)(b * 2048 + q0 + w * 32 + qf * 16 + lr) * 4096 + h * 128;
#pragma unroll
    for (int c = 0; c < 4; ++c)
      aq[qf][c] = *reinterpret_cast<const bf16x8*>(QKb + qrow + c * 32 + lh * 8);
  }

  f32x4 zero = {0.f, 0.f, 0.f, 0.f};
  f32x4 acc_o[2][8];
#pragma unroll
  for (int qf = 0; qf < 2; ++qf)
#pragma unroll
    for (int d = 0; d < 8; ++d) acc_o[qf][d] = zero;
  float m_row[2] = {-1e30f, -1e30f};
  float l_row[2] = {0.f, 0.f};

  auto stage = [&](int buf, int kt2) {
    const u16* Kt = Kbase + (size_t)(kt2 * 64) * 4096;
    const u16* Vt = Vbase + kt2 * 64;
#pragma unroll
    for (int it = 0; it < 4; ++it) {
      int o = it * 4096 + t * 16;
      int rowK = o >> 8;
      int cbK = (o & 255) ^ ((rowK & 7) << 4);
      async_load16((u16*)sK[buf] + (o >> 1), Kt + (size_t)rowK * 4096 + (cbK >> 1));
      int rowV = o >> 7;
      int cbV = (o & 127) ^ ((rowV & 7) << 4);
      async_load16((u16*)sV[buf] + (o >> 1), Vt + (size_t)rowV * 4096 + (cbV >> 1));
    }
  };

  stage(0, 0);
  __syncthreads();
  int cur = 0;

  for (int kt = 0; kt < 32; ++kt) {
    if (kt < 31) stage(cur ^ 1, kt + 1);

    const u16* sKc = sK[cur];
    const u16* sVc = sV[cur];

    f32x4 sacc[2][4];
#pragma unroll
    for (int qf = 0; qf < 2; ++qf)
#pragma unroll
      for (int g = 0; g < 4; ++g) sacc[qf][g] = zero;
    __builtin_amdgcn_s_setprio(1);
#pragma unroll
    for (int g = 0; g < 4; ++g) {
      int row = g * 16 + lr;
      int xr = lr7 << 4;
#pragma unroll
      for (int c = 0; c < 4; ++c) {
        int cb = (c * 64 + lh * 16) ^ xr;
        bf16x8 bk = *reinterpret_cast<const bf16x8*>(sKc + row * 128 + (cb >> 1));
        sacc[0][g] = __builtin_amdgcn_mfma_f32_16x16x32_bf16(bk, aq[0][c], sacc[0][g], 0, 0, 0);
        sacc[1][g] = __builtin_amdgcn_mfma_f32_16x16x32_bf16(bk, aq[1][c], sacc[1][g], 0, 0, 0);
      }
    }
    __builtin_amdgcn_s_setprio(0);

#pragma unroll
    for (int qf = 0; qf < 2; ++qf) {
      f32x4 m4;
#pragma unroll
      for (int e = 0; e < 4; ++e)
        m4[e] = fmaxf(fmaxf(sacc[qf][0][e], sacc[qf][1][e]),
                      fmaxf(sacc[qf][2][e], sacc[qf][3][e]));
      float mx = fmaxf(fmaxf(m4[0], m4[1]), fmaxf(m4[2], m4[3]));
      mx = fmaxf(mx, __shfl_xor(mx, 16));
      mx = fmaxf(mx, __shfl_xor(mx, 32));
      float mo = m_row[qf];
      if (!__all(mx <= mo + 8.f)) {     // T13 defer-max
        float mn = fmaxf(mo, mx);
        float al = __builtin_amdgcn_exp2f(mo - mn);
        m_row[qf] = mn;
        l_row[qf] *= al;
#pragma unroll
        for (int d = 0; d < 8; ++d) acc_o[qf][d] *= al;
      }
      float mn = m_row[qf];
#pragma unroll
      for (int g = 0; g < 4; ++g)
#pragma unroll
        for (int e = 0; e < 4; ++e)
          sacc[qf][g][e] = __builtin_amdgcn_exp2f(sacc[qf][g][e] - mn);
      f32x4 s4;
#pragma unroll
      for (int e = 0; e < 4; ++e)
        s4[e] = (sacc[qf][0][e] + sacc[qf][1][e]) + (sacc[qf][2][e] + sacc[qf][3][e]);
      float rs = (s4[0] + s4[1]) + (s4[2] + s4[3]);
      rs += __shfl_xor(rs, 16);
      rs += __shfl_xor(rs, 32);
      l_row[qf] += rs;

      int rowb = (qf * 16 + lr) * 128;
      int xw = lr7 << 4;
#pragma unroll
      for (int g = 0; g < 4; ++g) {
        uint2 pw;
        pw.x = cvtpk(sacc[qf][g][0], sacc[qf][g][1]);
        pw.y = cvtpk(sacc[qf][g][2], sacc[qf][g][3]);
        int cb = (g * 32 + lh * 8) ^ xw;
        *reinterpret_cast<uint2*>(reinterpret_cast<char*>(sPw) + rowb + cb) = pw;
      }
    }

    bf16x8 bp[2][2];
#pragma unroll
    for (int qf = 0; qf < 2; ++qf) {
      int rowb = (qf * 16 + lr) * 128;
      int xr = lr7 << 4;
#pragma unroll
      for (int c2 = 0; c2 < 2; ++c2) {
        int cb = (c2 * 64 + lh * 16) ^ xr;
        bp[qf][c2] = *reinterpret_cast<const bf16x8*>(
            reinterpret_cast<const char*>(sPw) + rowb + cb);
      }
    }
    __builtin_amdgcn_s_setprio(1);
#pragma unroll
    for (int c2 = 0; c2 < 2; ++c2) {
#pragma unroll
      for (int d = 0; d < 8; ++d) {
        int row = d * 16 + lr;
        int cb = (c2 * 64 + lh * 16) ^ (lr7 << 4);
        bf16x8 bv = *reinterpret_cast<const bf16x8*>(sVc + row * 64 + (cb >> 1));
        acc_o[0][d] = __builtin_amdgcn_mfma_f32_16x16x32_bf16(bv, bp[0][c2], acc_o[0][d], 0, 0, 0);
        acc_o[1][d] = __builtin_amdgcn_mfma_f32_16x16x32_bf16(bv, bp[1][c2], acc_o[1][d], 0, 0, 0);
      }
    }
    __builtin_amdgcn_s_setprio(0);

    __syncthreads();
    cur ^= 1;
  }

#pragma unroll
  for (int qf = 0; qf < 2; ++qf) {
    float inv = 1.f / l_row[qf];
    size_t qrow = (size_t)(b * 2048 + q0 + w * 32 + qf * 16 + lr) * 2048 + h * 128;
#pragma unroll
    for (int d = 0; d < 8; ++d) {
      ushort4 o;
      o.x = f2bf(acc_o[qf][d][0] * inv);
      o.y = f2bf(acc_o[qf][d][1] * inv);
      o.z = f2bf(acc_o[qf][d][2] * inv);
      o.w = f2bf(acc_o[qf][d][3] * inv);
      *reinterpret_cast<ushort4*>(Ob + qrow + d * 16 + lh * 4) = o;
    }
  }
}

extern "C" void kernel_launch(void* const* d_in, const int* in_sizes, int n_in,
                              void* d_out, int out_size, void* d_ws, size_t ws_size,
                              hipStream_t stream) {
  const float* x  = (const float*)d_in[0];
  const float* rc = (const float*)d_in[1];
  const float* rs = (const float*)d_in[2];
  const float* Wq = (const float*)d_in[3];
  const float* Wk = (const float*)d_in[4];
  const float* Wv = (const float*)d_in[5];
  const float* Wo = (const float*)d_in[6];
  float* out = (float*)d_out;
  char* ws = (char*)d_ws;
  const size_t MB = 1024 * 1024;
  u16* xb   = (u16*)(ws);            // 16 MB
  u16* Wqkb = (u16*)(ws + 16 * MB);  // 16 MB  [4096][2048] = [Wq;Wk]
  u16* Wvb  = (u16*)(ws + 32 * MB);  // 8 MB
  u16* Wob  = (u16*)(ws + 40 * MB);  // 8 MB
  u16* QKb  = (u16*)(ws + 48 * MB);  // 32 MB  [4096][4096]
  u16* VTb  = (u16*)(ws + 80 * MB);  // 16 MB  [2048][4096]
  u16* Ob   = (u16*)(ws + 16 * MB);  // 16 MB  (alias Wqkb, dead after QK GEMM)

  convert_all<<<24576, 256, 0, stream>>>(x, Wq, Wk, Wv, Wo, xb, Wqkb, Wvb, Wob);

  const float qscale = 0.08838834764831845f * 1.4426950408889634f;  // 1/sqrt(128)*log2(e)
  gemm_qkv256<<<512, 512, 0, stream>>>(xb, Wqkb, Wvb, QKb, VTb, rc, rs, qscale);

  attn_kernel<<<512, 256, 0, stream>>>(QKb, VTb, Ob);

  gemm_o<<<256, 512, 0, stream>>>(Ob, Wob, out);
}